// Round 3
// baseline (513.936 us; speedup 1.0000x reference)
//
#include <hip/hip_runtime.h>

#define V_N 30000
#define E_N 500000
#define H_N 4
#define F_N 32
#define NEG 0.2f

__device__ __forceinline__ float lrelu(float x) { return x > 0.f ? x : NEG * x; }

// ---------------------------------------------------------------------------
// Kernel A: node transforms — 4 matrices fused, outputs packed per node:
//   tab_s[node] = [h][ att(32f) | msg(32f) ]   (256 floats / node)
//   tab_d[node] = [h][ att(32f) | msg(32f) ]
// 32 lanes per (node,head) row; weights in LDS; input row broadcast via shfl.
// ---------------------------------------------------------------------------
__global__ __launch_bounds__(256) void node_xform(
    const float* __restrict__ nf,
    const float* __restrict__ Was, const float* __restrict__ bas,
    const float* __restrict__ Wad, const float* __restrict__ bad,
    const float* __restrict__ Wms, const float* __restrict__ bms,
    const float* __restrict__ Wmd, const float* __restrict__ bmd,
    float* __restrict__ tab_s, float* __restrict__ tab_d)
{
    __shared__ float w0[1024], w1[1024], w2[1024], w3[1024];
    int tid = threadIdx.x;
    for (int i = tid; i < 1024; i += 256) {
        w0[i] = Was[i]; w1[i] = Wad[i];
        w2[i] = Wms[i]; w3[i] = Wmd[i];
    }
    __syncthreads();
    int lane = tid & 31;
    int r = blockIdx.x * 8 + (tid >> 5);          // r = node*H + h
    if (r >= V_N * H_N) return;                   // exact division: never taken
    float x = nf[r * 32 + lane];
    float a0 = bas[lane], a1 = bad[lane];
    float a2 = bms[lane], a3 = bmd[lane];
    #pragma unroll
    for (int k = 0; k < 32; ++k) {
        float xk = __shfl(x, k, 32);
        a0 += xk * w0[k * 32 + lane];
        a1 += xk * w1[k * 32 + lane];
        a2 += xk * w2[k * 32 + lane];
        a3 += xk * w3[k * 32 + lane];
    }
    // r*64 = node*256 + h*64
    tab_s[(size_t)r * 64 + lane]      = a0;   // att
    tab_s[(size_t)r * 64 + 32 + lane] = a2;   // msg
    tab_d[(size_t)r * 64 + lane]      = a1;
    tab_d[(size_t)r * 64 + 32 + lane] = a3;
}

// ---------------------------------------------------------------------------
// Kernel B: single fused edge pass.
//   ea = ef@Wae+bae ; me = ef@Wme+bme  (one shfl sweep, two LDS mats)
//   per head: score -> ex = exp(score)  (no max shift: exactly equivalent)
//             atomicAdd ssum[dst,h] (lane 0)
//             atomicAdd feat[dst,h,:] += ex * lrelu(sm+dm+me)   (UNNORMALIZED)
// Normalization (divide by ssum) is deferred to finalize.
// ---------------------------------------------------------------------------
__global__ __launch_bounds__(256) void edge_fused(
    const float* __restrict__ ef, const int* __restrict__ src, const int* __restrict__ dst,
    const float* __restrict__ Wae, const float* __restrict__ bae,
    const float* __restrict__ Wdot, const float* __restrict__ bdot,
    const float* __restrict__ Wme, const float* __restrict__ bme,
    const float* __restrict__ tab_s, const float* __restrict__ tab_d,
    float* __restrict__ ssum, float* __restrict__ feat)
{
    __shared__ float wa[1024], wm[1024], wd[32];
    int tid = threadIdx.x;
    for (int i = tid; i < 1024; i += 256) { wa[i] = Wae[i]; wm[i] = Wme[i]; }
    if (tid < 32) wd[tid] = Wdot[tid];
    __syncthreads();
    int lane = tid & 31;
    int e = blockIdx.x * 8 + (tid >> 5);
    if (e >= E_N) return;                          // exact division: never taken
    float x = ef[(size_t)e * 32 + lane];
    float ea = bae[lane], me = bme[lane];
    #pragma unroll
    for (int k = 0; k < 32; ++k) {
        float xk = __shfl(x, k, 32);
        ea += xk * wa[k * 32 + lane];
        me += xk * wm[k * 32 + lane];
    }
    int si = src[e], di = dst[e];
    float bd = bdot[0];
    const float* sp = tab_s + (size_t)si * 256;
    const float* dp = tab_d + (size_t)di * 256;
    #pragma unroll
    for (int h = 0; h < H_N; ++h) {
        float sa = sp[h * 64 + lane],      da = dp[h * 64 + lane];
        float sm = sp[h * 64 + 32 + lane], dm = dp[h * 64 + 32 + lane];
        float t = lrelu(sa + da + ea) * wd[lane];
        #pragma unroll
        for (int off = 16; off; off >>= 1) t += __shfl_xor(t, off, 32);
        float exv = __expf(t + bd);                // all lanes hold same value
        if (lane == 0) atomicAdd(&ssum[(size_t)di * H_N + h], exv);
        float v = exv * lrelu(sm + dm + me);
        atomicAdd(&feat[((size_t)di * H_N + h) * 32 + lane], v);
    }
}

// ---------------------------------------------------------------------------
// Kernel C: out = lrelu(feat/ssum + nf @ W_wn + b_wn).
// ssum==0 guard (isolated node): ref's feat is 0 there -> use 0.
// ---------------------------------------------------------------------------
__global__ __launch_bounds__(256) void finalize_k(
    const float* __restrict__ nf, const float* __restrict__ Wwn, const float* __restrict__ bwn,
    const float* __restrict__ feat, const float* __restrict__ ssum,
    float* __restrict__ out)
{
    __shared__ float w[1024];
    int tid = threadIdx.x;
    for (int i = tid; i < 1024; i += 256) w[i] = Wwn[i];
    __syncthreads();
    int lane = tid & 31;
    int r = blockIdx.x * 8 + (tid >> 5);
    if (r >= V_N * H_N) return;                    // exact division: never taken
    float x = nf[(size_t)r * 32 + lane];
    float a = bwn[lane];
    #pragma unroll
    for (int k = 0; k < 32; ++k) a += __shfl(x, k, 32) * w[k * 32 + lane];
    float s = ssum[r];
    float f = (s > 0.f) ? feat[(size_t)r * 32 + lane] / s : 0.f;
    out[(size_t)r * 32 + lane] = lrelu(f + a);
}

extern "C" void kernel_launch(void* const* d_in, const int* in_sizes, int n_in,
                              void* d_out, int out_size, void* d_ws, size_t ws_size,
                              hipStream_t stream)
{
    const float* nf  = (const float*)d_in[0];
    const float* ef  = (const float*)d_in[1];
    const int*   src = (const int*)d_in[2];
    const int*   dst = (const int*)d_in[3];
    const float* Was = (const float*)d_in[4],  *bas = (const float*)d_in[5];
    const float* Wad = (const float*)d_in[6],  *bad = (const float*)d_in[7];
    const float* Wae = (const float*)d_in[8],  *bae = (const float*)d_in[9];
    const float* Wdot= (const float*)d_in[10], *bdot= (const float*)d_in[11];
    const float* Wms = (const float*)d_in[12], *bms = (const float*)d_in[13];
    const float* Wmd = (const float*)d_in[14], *bmd = (const float*)d_in[15];
    const float* Wme = (const float*)d_in[16], *bme = (const float*)d_in[17];
    const float* Wwn = (const float*)d_in[18], *bwn = (const float*)d_in[19];

    float* ws = (float*)d_ws;
    const size_t nrow = (size_t)V_N * H_N;          // 120000
    float* tab_s = ws;                              // nrow*64
    float* tab_d = tab_s + nrow * 64;               // nrow*64
    float* ssum  = tab_d + nrow * 64;               // nrow        (zeroed)
    float* feat  = ssum + nrow;                     // nrow*32     (zeroed)

    // ssum and feat are adjacent: one async zero-fill (graph-capture safe).
    hipMemsetAsync(ssum, 0, nrow * 33 * sizeof(float), stream);

    const int rb = (int)((nrow + 7) / 8);           // 15000 blocks
    const int eb = (E_N + 7) / 8;                   // 62500 blocks

    node_xform<<<rb, 256, 0, stream>>>(nf, Was, bas, Wad, bad, Wms, bms, Wmd, bmd,
                                       tab_s, tab_d);
    edge_fused<<<eb, 256, 0, stream>>>(ef, src, dst, Wae, bae, Wdot, bdot, Wme, bme,
                                       tab_s, tab_d, ssum, feat);
    finalize_k<<<rb, 256, 0, stream>>>(nf, Wwn, bwn, feat, ssum, (float*)d_out);
}

// Round 4
// 428.732 us; speedup vs baseline: 1.1987x; 1.1987x over previous
//
#include <hip/hip_runtime.h>

#define V_N 30000
#define E_N 500000
#define H_N 4
#define F_N 32
#define NEG 0.2f

__device__ __forceinline__ float lrelu(float x) { return x > 0.f ? x : NEG * x; }

// ---------------------------------------------------------------------------
// Kernel A: node transforms — 4 matrices fused.
// Output layout (gather-optimized, per node = 256 floats = 1 KB):
//   tab[node*256 + lane*8 + h]     = att value for head h, feature lane
//   tab[node*256 + lane*8 + 4 + h] = msg value for head h, feature lane
// So an edge endpoint read is TWO float4 loads per lane.
// ---------------------------------------------------------------------------
__global__ __launch_bounds__(256) void node_xform(
    const float* __restrict__ nf,
    const float* __restrict__ Was, const float* __restrict__ bas,
    const float* __restrict__ Wad, const float* __restrict__ bad,
    const float* __restrict__ Wms, const float* __restrict__ bms,
    const float* __restrict__ Wmd, const float* __restrict__ bmd,
    float* __restrict__ tab_s, float* __restrict__ tab_d)
{
    __shared__ float w0[1024], w1[1024], w2[1024], w3[1024];
    int tid = threadIdx.x;
    for (int i = tid; i < 1024; i += 256) {
        w0[i] = Was[i]; w1[i] = Wad[i];
        w2[i] = Wms[i]; w3[i] = Wmd[i];
    }
    __syncthreads();
    int lane = tid & 31;
    int r = blockIdx.x * 8 + (tid >> 5);          // r = node*4 + h
    if (r >= V_N * H_N) return;                   // exact division: never taken
    float x = nf[(size_t)r * 32 + lane];
    float a0 = bas[lane], a1 = bad[lane];
    float a2 = bms[lane], a3 = bmd[lane];
    #pragma unroll
    for (int k = 0; k < 32; ++k) {
        float xk = __shfl(x, k, 32);
        a0 += xk * w0[k * 32 + lane];
        a1 += xk * w1[k * 32 + lane];
        a2 += xk * w2[k * 32 + lane];
        a3 += xk * w3[k * 32 + lane];
    }
    int node = r >> 2, h = r & 3;
    size_t base = (size_t)node * 256 + lane * 8;
    tab_s[base + h]     = a0;   // att (src)
    tab_s[base + 4 + h] = a2;   // msg (src)
    tab_d[base + h]     = a1;   // att (dst)
    tab_d[base + 4 + h] = a3;   // msg (dst)
}

// ---------------------------------------------------------------------------
// Kernel B: single fused edge pass, grid-stride (weights staged once/block).
// Per edge: 2 index loads + 4 float4 gathers (all independent, issued early),
// one shfl GEMV for (ea, me), then 4 heads of pure-register compute,
// then 4 wave-wide feat atomics + one 4-lane ssum atomic.
// exp without max-shift: exp(s)/sum exp(s) is exactly equivalent, |s| small.
// ---------------------------------------------------------------------------
__global__ __launch_bounds__(256) void edge_fused(
    const float* __restrict__ ef, const int* __restrict__ src, const int* __restrict__ dst,
    const float* __restrict__ Wae, const float* __restrict__ bae,
    const float* __restrict__ Wdot, const float* __restrict__ bdot,
    const float* __restrict__ Wme, const float* __restrict__ bme,
    const float* __restrict__ tab_s, const float* __restrict__ tab_d,
    float* __restrict__ ssum, float* __restrict__ feat)
{
    __shared__ float wa[1024], wm[1024], wd[32];
    int tid = threadIdx.x;
    for (int i = tid; i < 1024; i += 256) { wa[i] = Wae[i]; wm[i] = Wme[i]; }
    if (tid < 32) wd[tid] = Wdot[tid];
    __syncthreads();
    int lane = tid & 31;
    int gid  = (blockIdx.x * 256 + tid) >> 5;      // global 32-lane group id
    int ngr  = (gridDim.x * 256) >> 5;
    float bd  = bdot[0];
    float ba  = bae[lane], bm = bme[lane];
    float wdl = wd[lane];

    for (int e = gid; e < E_N; e += ngr) {
        int si = src[e], di = dst[e];
        // ---- issue all gathers up front (4 x dwordx4 per lane) ----
        const float4* sp = (const float4*)(tab_s + (size_t)si * 256 + lane * 8);
        const float4* dp = (const float4*)(tab_d + (size_t)di * 256 + lane * 8);
        float4 sa4 = sp[0], sm4 = sp[1];
        float4 da4 = dp[0], dm4 = dp[1];
        float  x   = ef[(size_t)e * 32 + lane];
        // ---- edge GEMV (ea, me) ----
        float ea = ba, me = bm;
        #pragma unroll
        for (int k = 0; k < 32; ++k) {
            float xk = __shfl(x, k, 32);
            ea += xk * wa[k * 32 + lane];
            me += xk * wm[k * 32 + lane];
        }
        // ---- 4 heads, pure-register ----
        float t0 = lrelu(sa4.x + da4.x + ea) * wdl;
        float t1 = lrelu(sa4.y + da4.y + ea) * wdl;
        float t2 = lrelu(sa4.z + da4.z + ea) * wdl;
        float t3 = lrelu(sa4.w + da4.w + ea) * wdl;
        #pragma unroll
        for (int off = 16; off; off >>= 1) {
            t0 += __shfl_xor(t0, off, 32);
            t1 += __shfl_xor(t1, off, 32);
            t2 += __shfl_xor(t2, off, 32);
            t3 += __shfl_xor(t3, off, 32);
        }
        float ex0 = __expf(t0 + bd);
        float ex1 = __expf(t1 + bd);
        float ex2 = __expf(t2 + bd);
        float ex3 = __expf(t3 + bd);
        float v0 = ex0 * lrelu(sm4.x + dm4.x + me);
        float v1 = ex1 * lrelu(sm4.y + dm4.y + me);
        float v2 = ex2 * lrelu(sm4.z + dm4.z + me);
        float v3 = ex3 * lrelu(sm4.w + dm4.w + me);
        // ---- scatter ----
        float* fb = feat + (size_t)di * 128;
        atomicAdd(&fb[lane],       v0);
        atomicAdd(&fb[32 + lane],  v1);
        atomicAdd(&fb[64 + lane],  v2);
        atomicAdd(&fb[96 + lane],  v3);
        float sel = (lane == 0) ? ex0 : (lane == 1) ? ex1 : (lane == 2) ? ex2 : ex3;
        if (lane < 4) atomicAdd(&ssum[(size_t)di * 4 + lane], sel);
    }
}

// ---------------------------------------------------------------------------
// Kernel C: out = lrelu(feat/ssum + nf @ W_wn + b_wn).
// ssum==0 guard (isolated node): ref's feat is 0 there -> use 0.
// ---------------------------------------------------------------------------
__global__ __launch_bounds__(256) void finalize_k(
    const float* __restrict__ nf, const float* __restrict__ Wwn, const float* __restrict__ bwn,
    const float* __restrict__ feat, const float* __restrict__ ssum,
    float* __restrict__ out)
{
    __shared__ float w[1024];
    int tid = threadIdx.x;
    for (int i = tid; i < 1024; i += 256) w[i] = Wwn[i];
    __syncthreads();
    int lane = tid & 31;
    int r = blockIdx.x * 8 + (tid >> 5);
    if (r >= V_N * H_N) return;                    // exact division: never taken
    float x = nf[(size_t)r * 32 + lane];
    float a = bwn[lane];
    #pragma unroll
    for (int k = 0; k < 32; ++k) a += __shfl(x, k, 32) * w[k * 32 + lane];
    float s = ssum[r];
    float f = (s > 0.f) ? feat[(size_t)r * 32 + lane] / s : 0.f;
    out[(size_t)r * 32 + lane] = lrelu(f + a);
}

extern "C" void kernel_launch(void* const* d_in, const int* in_sizes, int n_in,
                              void* d_out, int out_size, void* d_ws, size_t ws_size,
                              hipStream_t stream)
{
    const float* nf  = (const float*)d_in[0];
    const float* ef  = (const float*)d_in[1];
    const int*   src = (const int*)d_in[2];
    const int*   dst = (const int*)d_in[3];
    const float* Was = (const float*)d_in[4],  *bas = (const float*)d_in[5];
    const float* Wad = (const float*)d_in[6],  *bad = (const float*)d_in[7];
    const float* Wae = (const float*)d_in[8],  *bae = (const float*)d_in[9];
    const float* Wdot= (const float*)d_in[10], *bdot= (const float*)d_in[11];
    const float* Wms = (const float*)d_in[12], *bms = (const float*)d_in[13];
    const float* Wmd = (const float*)d_in[14], *bmd = (const float*)d_in[15];
    const float* Wme = (const float*)d_in[16], *bme = (const float*)d_in[17];
    const float* Wwn = (const float*)d_in[18], *bwn = (const float*)d_in[19];

    float* ws = (float*)d_ws;
    const size_t nrow = (size_t)V_N * H_N;          // 120000
    float* tab_s = ws;                              // V*256
    float* tab_d = tab_s + (size_t)V_N * 256;       // V*256
    float* ssum  = tab_d + (size_t)V_N * 256;       // nrow        (zeroed)
    float* feat  = ssum + nrow;                     // nrow*32     (zeroed)

    // ssum and feat are adjacent: one async zero-fill (graph-capture safe).
    hipMemsetAsync(ssum, 0, nrow * 33 * sizeof(float), stream);

    const int rb = (int)((nrow + 7) / 8);           // 15000 blocks
    const int eb = 2048;                            // grid-stride edge pass

    node_xform<<<rb, 256, 0, stream>>>(nf, Was, bas, Wad, bad, Wms, bms, Wmd, bmd,
                                       tab_s, tab_d);
    edge_fused<<<eb, 256, 0, stream>>>(ef, src, dst, Wae, bae, Wdot, bdot, Wme, bme,
                                       tab_s, tab_d, ssum, feat);
    finalize_k<<<rb, 256, 0, stream>>>(nf, Wwn, bwn, feat, ssum, (float*)d_out);
}

// Round 5
// 374.911 us; speedup vs baseline: 1.3708x; 1.1436x over previous
//
#include <hip/hip_runtime.h>

#define V_N 30000
#define E_N 500000
#define H_N 4
#define F_N 32
#define NEG 0.2f

__device__ __forceinline__ float lrelu(float x) { return x > 0.f ? x : NEG * x; }

// ---------------------------------------------------------------------------
// Kernel A: node transforms — 4 matrices fused.
// Output layout (gather-optimized, per node = 256 floats = 1 KB):
//   tab[node*256 + lane*8 + h]     = att value for head h, feature lane
//   tab[node*256 + lane*8 + 4 + h] = msg value for head h, feature lane
// ---------------------------------------------------------------------------
__global__ __launch_bounds__(256) void node_xform(
    const float* __restrict__ nf,
    const float* __restrict__ Was, const float* __restrict__ bas,
    const float* __restrict__ Wad, const float* __restrict__ bad,
    const float* __restrict__ Wms, const float* __restrict__ bms,
    const float* __restrict__ Wmd, const float* __restrict__ bmd,
    float* __restrict__ tab_s, float* __restrict__ tab_d)
{
    __shared__ float w0[1024], w1[1024], w2[1024], w3[1024];
    int tid = threadIdx.x;
    for (int i = tid; i < 1024; i += 256) {
        w0[i] = Was[i]; w1[i] = Wad[i];
        w2[i] = Wms[i]; w3[i] = Wmd[i];
    }
    __syncthreads();
    int lane = tid & 31;
    int r = blockIdx.x * 8 + (tid >> 5);          // r = node*4 + h
    if (r >= V_N * H_N) return;                   // exact: never taken
    float x = nf[(size_t)r * 32 + lane];
    float a0 = bas[lane], a1 = bad[lane];
    float a2 = bms[lane], a3 = bmd[lane];
    #pragma unroll
    for (int k = 0; k < 32; ++k) {
        float xk = __shfl(x, k, 32);
        a0 += xk * w0[k * 32 + lane];
        a1 += xk * w1[k * 32 + lane];
        a2 += xk * w2[k * 32 + lane];
        a3 += xk * w3[k * 32 + lane];
    }
    int node = r >> 2, h = r & 3;
    size_t base = (size_t)node * 256 + lane * 8;
    tab_s[base + h]     = a0;   // att (src path)
    tab_s[base + 4 + h] = a2;   // msg (src path)
    tab_d[base + h]     = a1;   // att (dst path)
    tab_d[base + 4 + h] = a3;   // msg (dst path)
}

// ---------------------------------------------------------------------------
// CSR build: histogram -> exclusive scan -> scatter edge ids by dst.
// ---------------------------------------------------------------------------
__global__ __launch_bounds__(256) void hist_k(
    const int* __restrict__ dst, int* __restrict__ deg)
{
    int i = blockIdx.x * 256 + threadIdx.x;
    if (i < E_N) atomicAdd(&deg[dst[i]], 1);
}

__global__ __launch_bounds__(1024) void scan_k(
    const int* __restrict__ deg, int* __restrict__ rowptr, int* __restrict__ cursor)
{
    __shared__ int wsum[16];
    __shared__ int carry_s;
    int tid = threadIdx.x;
    int lane = tid & 63, wv = tid >> 6;
    if (tid == 0) carry_s = 0;
    __syncthreads();
    for (int base = 0; base < V_N; base += 1024) {
        int i = base + tid;
        int v = (i < V_N) ? deg[i] : 0;
        int x = v;
        #pragma unroll
        for (int off = 1; off < 64; off <<= 1) {     // wave64 inclusive scan
            int t = __shfl_up(x, off, 64);
            if (lane >= off) x += t;
        }
        if (lane == 63) wsum[wv] = x;
        __syncthreads();
        if (wv == 0 && lane < 16) {                  // scan the 16 wave totals
            int s = wsum[lane];
            #pragma unroll
            for (int off = 1; off < 16; off <<= 1) {
                int t = __shfl_up(s, off, 64);
                if (lane >= off) s += t;
            }
            wsum[lane] = s;
        }
        __syncthreads();
        int woff  = (wv == 0) ? 0 : wsum[wv - 1];
        int carry = carry_s;
        int excl  = carry + woff + x - v;
        if (i < V_N) { rowptr[i] = excl; cursor[i] = excl; }
        __syncthreads();                             // all read carry_s first
        if (tid == 1023) carry_s = carry + wsum[15];
        __syncthreads();
    }
    if (tid == 0) rowptr[V_N] = carry_s;             // == E_N
}

__global__ __launch_bounds__(256) void scatter_k(
    const int* __restrict__ dst, int* __restrict__ cursor, int* __restrict__ eidx)
{
    int i = blockIdx.x * 256 + threadIdx.x;
    if (i < E_N) {
        int p = atomicAdd(&cursor[dst[i]], 1);
        eidx[p] = i;
    }
}

// ---------------------------------------------------------------------------
// Kernel B: per-dst-node aggregation (NO atomics) + fused finalize.
// One 32-lane group per node: load dst entry once, loop incoming edges,
// accumulate exp-weighted messages + softmax denom in registers, then
// apply W_wn GEMV and write out directly.
// exp without max-shift: exp(s)/sum exp(s) is exactly equivalent, |s| small.
// ---------------------------------------------------------------------------
__global__ __launch_bounds__(256) void node_gather(
    const float* __restrict__ ef, const int* __restrict__ src,
    const int* __restrict__ rowptr, const int* __restrict__ eidx,
    const float* __restrict__ Wae, const float* __restrict__ bae,
    const float* __restrict__ Wdot, const float* __restrict__ bdot,
    const float* __restrict__ Wme, const float* __restrict__ bme,
    const float* __restrict__ Wwn, const float* __restrict__ bwn,
    const float* __restrict__ nf,
    const float* __restrict__ tab_s, const float* __restrict__ tab_d,
    float* __restrict__ out)
{
    __shared__ float wa[1024], wm[1024], ww[1024], wd[32];
    int tid = threadIdx.x;
    for (int i = tid; i < 1024; i += 256) { wa[i] = Wae[i]; wm[i] = Wme[i]; ww[i] = Wwn[i]; }
    if (tid < 32) wd[tid] = Wdot[tid];
    __syncthreads();
    int lane = tid & 31;
    int n = blockIdx.x * 8 + (tid >> 5);
    if (n >= V_N) return;                            // 3750*8 = 30000 exact
    float bd  = bdot[0];
    float ba  = bae[lane], bm = bme[lane];
    float wdl = wd[lane];
    const float4* dp = (const float4*)(tab_d + (size_t)n * 256 + lane * 8);
    float4 da4 = dp[0], dm4 = dp[1];
    float acc0 = 0.f, acc1 = 0.f, acc2 = 0.f, acc3 = 0.f;
    float s0 = 0.f, s1 = 0.f, s2 = 0.f, s3 = 0.f;
    int p0 = rowptr[n], p1 = rowptr[n + 1];
    for (int p = p0; p < p1; ++p) {
        int e  = eidx[p];
        int si = src[e];
        const float4* sp = (const float4*)(tab_s + (size_t)si * 256 + lane * 8);
        float4 sa4 = sp[0], sm4 = sp[1];
        float  x   = ef[(size_t)e * 32 + lane];
        float ea = ba, me = bm;
        #pragma unroll
        for (int k = 0; k < 32; ++k) {
            float xk = __shfl(x, k, 32);
            ea += xk * wa[k * 32 + lane];
            me += xk * wm[k * 32 + lane];
        }
        float t0 = lrelu(sa4.x + da4.x + ea) * wdl;
        float t1 = lrelu(sa4.y + da4.y + ea) * wdl;
        float t2 = lrelu(sa4.z + da4.z + ea) * wdl;
        float t3 = lrelu(sa4.w + da4.w + ea) * wdl;
        #pragma unroll
        for (int off = 16; off; off >>= 1) {
            t0 += __shfl_xor(t0, off, 32);
            t1 += __shfl_xor(t1, off, 32);
            t2 += __shfl_xor(t2, off, 32);
            t3 += __shfl_xor(t3, off, 32);
        }
        float ex0 = __expf(t0 + bd);
        float ex1 = __expf(t1 + bd);
        float ex2 = __expf(t2 + bd);
        float ex3 = __expf(t3 + bd);
        acc0 += ex0 * lrelu(sm4.x + dm4.x + me);
        acc1 += ex1 * lrelu(sm4.y + dm4.y + me);
        acc2 += ex2 * lrelu(sm4.z + dm4.z + me);
        acc3 += ex3 * lrelu(sm4.w + dm4.w + me);
        s0 += ex0; s1 += ex1; s2 += ex2; s3 += ex3;
    }
    // fused finalize: out = lrelu(feat/ssum + nf@Wwn + bwn), per head
    size_t rb = (size_t)n * 128;
    #pragma unroll
    for (int h = 0; h < 4; ++h) {
        float x = nf[rb + h * 32 + lane];
        float a = bwn[lane];
        #pragma unroll
        for (int k = 0; k < 32; ++k) a += __shfl(x, k, 32) * ww[k * 32 + lane];
        float acch = (h == 0) ? acc0 : (h == 1) ? acc1 : (h == 2) ? acc2 : acc3;
        float sh   = (h == 0) ? s0   : (h == 1) ? s1   : (h == 2) ? s2   : s3;
        float f = (sh > 0.f) ? acch / sh : 0.f;
        out[rb + h * 32 + lane] = lrelu(f + a);
    }
}

extern "C" void kernel_launch(void* const* d_in, const int* in_sizes, int n_in,
                              void* d_out, int out_size, void* d_ws, size_t ws_size,
                              hipStream_t stream)
{
    const float* nf  = (const float*)d_in[0];
    const float* ef  = (const float*)d_in[1];
    const int*   src = (const int*)d_in[2];
    const int*   dst = (const int*)d_in[3];
    const float* Was = (const float*)d_in[4],  *bas = (const float*)d_in[5];
    const float* Wad = (const float*)d_in[6],  *bad = (const float*)d_in[7];
    const float* Wae = (const float*)d_in[8],  *bae = (const float*)d_in[9];
    const float* Wdot= (const float*)d_in[10], *bdot= (const float*)d_in[11];
    const float* Wms = (const float*)d_in[12], *bms = (const float*)d_in[13];
    const float* Wmd = (const float*)d_in[14], *bmd = (const float*)d_in[15];
    const float* Wme = (const float*)d_in[16], *bme = (const float*)d_in[17];
    const float* Wwn = (const float*)d_in[18], *bwn = (const float*)d_in[19];

    float* ws = (float*)d_ws;
    float* tab_s = ws;                               // V*256 f
    float* tab_d = tab_s + (size_t)V_N * 256;        // V*256 f
    int* deg    = (int*)(tab_d + (size_t)V_N * 256); // V
    int* rowptr = deg + V_N;                         // V+1
    int* cursor = rowptr + V_N + 1;                  // V
    int* eidx   = cursor + V_N;                      // E

    hipMemsetAsync(deg, 0, V_N * sizeof(int), stream);

    const int rb = (V_N * H_N + 7) / 8;              // 15000 blocks
    const int ebk = (E_N + 255) / 256;               // 1954 blocks
    const int nb = (V_N + 7) / 8;                    // 3750 blocks

    node_xform<<<rb, 256, 0, stream>>>(nf, Was, bas, Wad, bad, Wms, bms, Wmd, bmd,
                                       tab_s, tab_d);
    hist_k<<<ebk, 256, 0, stream>>>(dst, deg);
    scan_k<<<1, 1024, 0, stream>>>(deg, rowptr, cursor);
    scatter_k<<<ebk, 256, 0, stream>>>(dst, cursor, eidx);
    node_gather<<<nb, 256, 0, stream>>>(ef, src, rowptr, eidx,
                                        Wae, bae, Wdot, bdot, Wme, bme, Wwn, bwn,
                                        nf, tab_s, tab_d, (float*)d_out);
}